// Round 2
// baseline (678.283 us; speedup 1.0000x reference)
//
#include <hip/hip_runtime.h>
#include <hip/hip_bf16.h>

#define BB   2
#define TT   512
#define NF   6
#define DD   32
#define HIDD 128
#define NHH  4
#define HDD  32
#define GHH  32
#define FDD  128
#define LL   (TT*NF)      // 3072
#define EPSF 1e-5f

// ---------------------------------------------------------------------------
// Kernel 1: per-token gater (LN -> 32x32 MLP -> sigmoid) + gated QKV proj.
// One wave (64 threads) per token. 6144 blocks.
// ---------------------------------------------------------------------------
__global__ __launch_bounds__(64) void gate_qkv_kernel(
    const float* __restrict__ x,
    const float* __restrict__ g_ln_w, const float* __restrict__ g_ln_b,
    const float* __restrict__ g_w1,   const float* __restrict__ g_b1,
    const float* __restrict__ g_w2,   const float* __restrict__ g_b2,
    const float* __restrict__ q_w,    const float* __restrict__ q_b,
    const float* __restrict__ k_w,    const float* __restrict__ k_b,
    const float* __restrict__ v_w,    const float* __restrict__ v_b,
    float* __restrict__ Q, float* __restrict__ K, float* __restrict__ V)
{
    const int tok  = blockIdx.x;
    const int lane = threadIdx.x;

    __shared__ float xs[DD];
    __shared__ float lns[DD];
    __shared__ float hs[GHH];
    __shared__ float gate_s;

    if (lane < DD) {
        float xv = x[(size_t)tok * DD + lane];
        xs[lane] = xv;
        float s1 = xv, s2 = xv * xv;
        #pragma unroll
        for (int m = 16; m >= 1; m >>= 1) {
            s1 += __shfl_xor(s1, m, 32);
            s2 += __shfl_xor(s2, m, 32);
        }
        float mu  = s1 * (1.0f / DD);
        float var = s2 * (1.0f / DD) - mu * mu;
        float r   = rsqrtf(var + EPSF);
        lns[lane] = (xv - mu) * r * g_ln_w[lane] + g_ln_b[lane];
    }
    __syncthreads();

    if (lane < GHH) {
        float acc = g_b1[lane];
        #pragma unroll
        for (int d = 0; d < DD; d++) acc += lns[d] * g_w1[d * GHH + lane];
        hs[lane] = acc / (1.0f + __expf(-acc));   // SiLU
    }
    __syncthreads();

    if (lane < GHH) {
        float p = hs[lane] * g_w2[lane];
        #pragma unroll
        for (int m = 16; m >= 1; m >>= 1) p += __shfl_xor(p, m, 32);
        if (lane == 0) gate_s = 1.0f / (1.0f + __expf(-(p + g_b2[0])));
    }
    __syncthreads();

    const float g = gate_s;

    float aq0 = q_b[lane], aq1 = q_b[lane + 64];
    float ak0 = k_b[lane], ak1 = k_b[lane + 64];
    float av0 = v_b[lane], av1 = v_b[lane + 64];
    #pragma unroll
    for (int d = 0; d < DD; d++) {
        float xd = xs[d];
        aq0 += xd * q_w[d * HIDD + lane];
        aq1 += xd * q_w[d * HIDD + lane + 64];
        ak0 += xd * k_w[d * HIDD + lane];
        ak1 += xd * k_w[d * HIDD + lane + 64];
        av0 += xd * v_w[d * HIDD + lane];
        av1 += xd * v_w[d * HIDD + lane + 64];
    }
    const size_t base = (size_t)tok * HIDD;
    Q[base + lane] = aq0 * g;  Q[base + lane + 64] = aq1 * g;
    K[base + lane] = ak0 * g;  K[base + lane + 64] = ak1 * g;
    V[base + lane] = av0 * g;  V[base + lane + 64] = av1 * g;
}

// ---------------------------------------------------------------------------
// Kernel 2: flash attention with block-causal prefix mask.
// Block = (q-tile of 64 rows, head, batch). 256 threads = 64 rows x 4 subs.
// Each group of 4 lanes owns one query row; each lane owns 8 of 32 dims.
// Causal structure: row i attends exactly keys j < 6*(i/6+1) (contiguous
// prefix), so masking is just a per-row loop bound.
// ---------------------------------------------------------------------------
__global__ __launch_bounds__(256) void attn_kernel(
    const float* __restrict__ Q, const float* __restrict__ K,
    const float* __restrict__ V, float* __restrict__ O)
{
    const int qt  = blockIdx.x;        // 0..47
    const int h   = blockIdx.y;        // 0..3
    const int b   = blockIdx.z;        // 0..1
    const int tid = threadIdx.x;
    const int row = tid >> 2;          // local query row 0..63
    const int sub = tid & 3;           // dim group: dims sub*8 .. sub*8+7
    const int ig  = qt * 64 + row;     // global query index

    // row stride 36 floats (144 B): 16B-aligned rows, conflict-spread b128
    // writes + same-addr broadcast reads.
    __shared__ __align__(16) float Kt[64][36];
    __shared__ __align__(16) float Vt[64][36];

    const float scale = 0.17677669529663688f;  // 1/sqrt(32)
    float q[8], o[8];
    const size_t qbase = ((size_t)(b * LL + ig)) * HIDD + h * HDD + sub * 8;
    #pragma unroll
    for (int i = 0; i < 8; i++) { q[i] = Q[qbase + i] * scale; o[i] = 0.0f; }

    float m = -INFINITY, l = 0.0f;
    const int jmax      = (ig / NF + 1) * NF;               // exclusive prefix end
    const int jmax_tile = ((qt * 64 + 63) / NF + 1) * NF;   // max over tile rows
    const int ntiles    = (jmax_tile + 63) >> 6;

    for (int kt = 0; kt < ntiles; kt++) {
        const int j0 = kt * 64;
        __syncthreads();   // protect LDS reuse from previous iteration
        #pragma unroll
        for (int rr = 0; rr < 2; rr++) {
            int idx = tid + rr * 256;      // 512 float4 slots
            int jr  = idx >> 3;            // key row 0..63
            int c4  = idx & 7;             // float4 column
            size_t gb = ((size_t)(b * LL + j0 + jr)) * HIDD + h * HDD;
            float4 kv = *((const float4*)(K + gb) + c4);
            float4 vv = *((const float4*)(V + gb) + c4);
            *((float4*)(&Kt[jr][0]) + c4) = kv;
            *((float4*)(&Vt[jr][0]) + c4) = vv;
        }
        __syncthreads();

        const int jend = min(64, jmax - j0);   // <=0: this row is done
        for (int j = 0; j < jend; j++) {
            const float* kr = &Kt[j][sub * 8];
            float p = q[0]*kr[0] + q[1]*kr[1] + q[2]*kr[2] + q[3]*kr[3]
                    + q[4]*kr[4] + q[5]*kr[5] + q[6]*kr[6] + q[7]*kr[7];
            p += __shfl_xor(p, 1);     // 4-lane reduce (stays inside group)
            p += __shfl_xor(p, 2);
            float mn   = fmaxf(m, p);
            float corr = __expf(m - mn);   // m=-inf first iter -> corr=0
            float pe   = __expf(p - mn);
            l = l * corr + pe;
            m = mn;
            const float* vr = &Vt[j][sub * 8];
            #pragma unroll
            for (int i = 0; i < 8; i++) o[i] = o[i] * corr + pe * vr[i];
        }
    }

    const float inv = 1.0f / l;   // every row attends >=6 keys, l > 0
    const size_t ob = ((size_t)(b * LL + ig)) * HIDD + h * HDD + sub * 8;
    #pragma unroll
    for (int i = 0; i < 8; i++) O[ob + i] = o[i] * inv;
}

// ---------------------------------------------------------------------------
// Kernel 3: mean-pool over forces (commutes with o-proj) -> o-proj -> LN ->
// f-proj -> SiLU -> fp32 out. Block per (t, b), 128 threads (one per channel).
// ---------------------------------------------------------------------------
__global__ __launch_bounds__(128) void final_kernel(
    const float* __restrict__ A,
    const float* __restrict__ o_w,    const float* __restrict__ o_b,
    const float* __restrict__ f_ln_w, const float* __restrict__ f_ln_b,
    const float* __restrict__ f_w,    const float* __restrict__ f_b,
    float* __restrict__ out)
{
    const int t = blockIdx.x;
    const int b = blockIdx.y;
    const int d = threadIdx.x;   // 0..127

    __shared__ float ms[HIDD];
    __shared__ float lnbuf[HIDD];
    __shared__ float w1[2], w2[2];

    float acc = 0.0f;
    #pragma unroll
    for (int f = 0; f < NF; f++)
        acc += A[((size_t)(b * LL + t * NF + f)) * HIDD + d];
    acc *= (1.0f / NF);
    ms[d] = acc;
    __syncthreads();

    float ov = o_b[d];
    for (int k = 0; k < HIDD; k++) ov += ms[k] * o_w[k * HIDD + d];

    // LayerNorm over the 128 channels (2 waves -> LDS combine)
    float s1 = ov, s2 = ov * ov;
    #pragma unroll
    for (int m = 32; m >= 1; m >>= 1) { s1 += __shfl_xor(s1, m); s2 += __shfl_xor(s2, m); }
    if ((d & 63) == 0) { w1[d >> 6] = s1; w2[d >> 6] = s2; }
    __syncthreads();
    float S1 = w1[0] + w1[1], S2 = w2[0] + w2[1];
    float mu  = S1 * (1.0f / HIDD);
    float var = S2 * (1.0f / HIDD) - mu * mu;
    float r   = rsqrtf(var + EPSF);
    float lnv = (ov - mu) * r * f_ln_w[d] + f_ln_b[d];
    lnbuf[d] = lnv;
    __syncthreads();

    float fv = f_b[d];
    for (int k = 0; k < HIDD; k++) fv += lnbuf[k] * f_w[k * HIDD + d];
    fv = fv / (1.0f + __expf(-fv));   // SiLU

    out[((size_t)(b * TT + t)) * FDD + d] = fv;
}

// ---------------------------------------------------------------------------
extern "C" void kernel_launch(void* const* d_in, const int* in_sizes, int n_in,
                              void* d_out, int out_size, void* d_ws, size_t ws_size,
                              hipStream_t stream)
{
    const float* x      = (const float*)d_in[0];
    const float* g_ln_w = (const float*)d_in[1];
    const float* g_ln_b = (const float*)d_in[2];
    const float* g_w1   = (const float*)d_in[3];
    const float* g_b1   = (const float*)d_in[4];
    const float* g_w2   = (const float*)d_in[5];
    const float* g_b2   = (const float*)d_in[6];
    const float* q_w    = (const float*)d_in[7];
    const float* q_b    = (const float*)d_in[8];
    const float* k_w    = (const float*)d_in[9];
    const float* k_b    = (const float*)d_in[10];
    const float* v_w    = (const float*)d_in[11];
    const float* v_b    = (const float*)d_in[12];
    const float* o_w    = (const float*)d_in[13];
    const float* o_b    = (const float*)d_in[14];
    const float* f_ln_w = (const float*)d_in[15];
    const float* f_ln_b = (const float*)d_in[16];
    const float* f_w    = (const float*)d_in[17];
    const float* f_b    = (const float*)d_in[18];

    const size_t stride = (size_t)BB * LL * HIDD;   // 786432 floats
    float* Qw = (float*)d_ws;
    float* Kw = Qw + stride;
    float* Vw = Kw + stride;
    float* Aw = Vw + stride;                        // total 12.6 MB of d_ws

    gate_qkv_kernel<<<BB * LL, 64, 0, stream>>>(
        x, g_ln_w, g_ln_b, g_w1, g_b1, g_w2, g_b2,
        q_w, q_b, k_w, k_b, v_w, v_b, Qw, Kw, Vw);

    attn_kernel<<<dim3(LL / 64, NHH, BB), 256, 0, stream>>>(Qw, Kw, Vw, Aw);

    final_kernel<<<dim3(TT, BB), 128, 0, stream>>>(
        Aw, o_w, o_b, f_ln_w, f_ln_b, f_w, f_b, (float*)d_out);
}

// Round 3
// 314.852 us; speedup vs baseline: 2.1543x; 2.1543x over previous
//
#include <hip/hip_runtime.h>
#include <hip/hip_bf16.h>

#define BB   2
#define TT   512
#define NF   6
#define DD   32
#define HIDD 128
#define NHH  4
#define HDD  32
#define GHH  32
#define FDD  128
#define LL   (TT*NF)      // 3072
#define EPSF 1e-5f

// ---------------------------------------------------------------------------
// Kernel 1: per-token gater (LN -> 32x32 MLP -> sigmoid) + gated QKV proj.
// One wave (64 threads) per token. 6144 blocks.
// ---------------------------------------------------------------------------
__global__ __launch_bounds__(64) void gate_qkv_kernel(
    const float* __restrict__ x,
    const float* __restrict__ g_ln_w, const float* __restrict__ g_ln_b,
    const float* __restrict__ g_w1,   const float* __restrict__ g_b1,
    const float* __restrict__ g_w2,   const float* __restrict__ g_b2,
    const float* __restrict__ q_w,    const float* __restrict__ q_b,
    const float* __restrict__ k_w,    const float* __restrict__ k_b,
    const float* __restrict__ v_w,    const float* __restrict__ v_b,
    float* __restrict__ Q, float* __restrict__ K, float* __restrict__ V)
{
    const int tok  = blockIdx.x;
    const int lane = threadIdx.x;

    __shared__ float xs[DD];
    __shared__ float lns[DD];
    __shared__ float hs[GHH];
    __shared__ float gate_s;

    if (lane < DD) {
        float xv = x[(size_t)tok * DD + lane];
        xs[lane] = xv;
        float s1 = xv, s2 = xv * xv;
        #pragma unroll
        for (int m = 16; m >= 1; m >>= 1) {
            s1 += __shfl_xor(s1, m, 32);
            s2 += __shfl_xor(s2, m, 32);
        }
        float mu  = s1 * (1.0f / DD);
        float var = s2 * (1.0f / DD) - mu * mu;
        float r   = rsqrtf(var + EPSF);
        lns[lane] = (xv - mu) * r * g_ln_w[lane] + g_ln_b[lane];
    }
    __syncthreads();

    if (lane < GHH) {
        float acc = g_b1[lane];
        #pragma unroll
        for (int d = 0; d < DD; d++) acc += lns[d] * g_w1[d * GHH + lane];
        hs[lane] = acc / (1.0f + __expf(-acc));   // SiLU
    }
    __syncthreads();

    if (lane < GHH) {
        float p = hs[lane] * g_w2[lane];
        #pragma unroll
        for (int m = 16; m >= 1; m >>= 1) p += __shfl_xor(p, m, 32);
        if (lane == 0) gate_s = 1.0f / (1.0f + __expf(-(p + g_b2[0])));
    }
    __syncthreads();

    const float g = gate_s;

    float aq0 = q_b[lane], aq1 = q_b[lane + 64];
    float ak0 = k_b[lane], ak1 = k_b[lane + 64];
    float av0 = v_b[lane], av1 = v_b[lane + 64];
    #pragma unroll
    for (int d = 0; d < DD; d++) {
        float xd = xs[d];
        aq0 += xd * q_w[d * HIDD + lane];
        aq1 += xd * q_w[d * HIDD + lane + 64];
        ak0 += xd * k_w[d * HIDD + lane];
        ak1 += xd * k_w[d * HIDD + lane + 64];
        av0 += xd * v_w[d * HIDD + lane];
        av1 += xd * v_w[d * HIDD + lane + 64];
    }
    const size_t base = (size_t)tok * HIDD;
    Q[base + lane] = aq0 * g;  Q[base + lane + 64] = aq1 * g;
    K[base + lane] = ak0 * g;  K[base + lane + 64] = ak1 * g;
    V[base + lane] = av0 * g;  V[base + lane + 64] = av1 * g;
}

// ---------------------------------------------------------------------------
// Kernel 2: flash attention, batched-tile softmax.
// Block = (32 q-rows, head, batch), 256 threads = 32 rows x 8 grp.
// Each thread: full q[32] in regs, 8 keys/tile (j = jj*8+grp), private
// o_partial[32] over its own keys; cross-thread traffic per tile = one max.
// Causal prefix: row i attends exactly j < 6*(i/6+1) -> per-key predicate.
// Heavy tiles launched first (qt reversed) to kill the tail.
// ---------------------------------------------------------------------------
__global__ __launch_bounds__(256) void attn_kernel(
    const float* __restrict__ Q, const float* __restrict__ K,
    const float* __restrict__ V, float* __restrict__ O)
{
    const int qt  = (LL/32 - 1) - blockIdx.x;   // 95..0, heavy first
    const int h   = blockIdx.y;
    const int b   = blockIdx.z;
    const int tid = threadIdx.x;
    const int row = tid >> 3;          // 0..31
    const int grp = tid & 7;           // 0..7
    const int ig  = qt * 32 + row;

    // stride 36 floats: rows 16B-aligned; j consecutive within a wave-instr
    // -> 4j mod 32 walks all bank groups, conflict-free + 8-way broadcast.
    __shared__ __align__(16) float Kt[64][36];
    __shared__ __align__(16) float Vt[64][36];

    const float scale = 0.17677669529663688f;  // 1/sqrt(32)
    float q[32], o[32];
    const size_t qbase = ((size_t)(b * LL + ig)) * HIDD + h * HDD;
    #pragma unroll
    for (int i = 0; i < 8; i++) {
        float4 t = *((const float4*)(Q + qbase) + i);
        q[4*i+0] = t.x * scale; q[4*i+1] = t.y * scale;
        q[4*i+2] = t.z * scale; q[4*i+3] = t.w * scale;
    }
    #pragma unroll
    for (int i = 0; i < 32; i++) o[i] = 0.0f;

    float m = -1e30f, l = 0.0f;
    const int jmax      = (ig / NF + 1) * NF;               // exclusive prefix end
    const int jmax_tile = ((qt * 32 + 31) / NF + 1) * NF;   // max over tile rows
    const int ntiles    = (jmax_tile + 63) >> 6;

    for (int kt = 0; kt < ntiles; kt++) {
        const int j0 = kt * 64;
        __syncthreads();
        #pragma unroll
        for (int rr = 0; rr < 2; rr++) {
            int idx = tid + rr * 256;      // 512 float4 slots
            int jr  = idx >> 3;
            int c4  = idx & 7;
            size_t gb = ((size_t)(b * LL + j0 + jr)) * HIDD + h * HDD;
            *((float4*)(&Kt[jr][0]) + c4) = *((const float4*)(K + gb) + c4);
            *((float4*)(&Vt[jr][0]) + c4) = *((const float4*)(V + gb) + c4);
        }
        __syncthreads();

        const int jend = jmax - j0;   // per-row valid-key bound in this tile
        float p[8];
        #pragma unroll
        for (int jj = 0; jj < 8; jj++) {
            const int j = jj * 8 + grp;
            const float* kr = &Kt[j][0];
            float acc = 0.0f;
            #pragma unroll
            for (int d = 0; d < 32; d++) acc += q[d] * kr[d];
            p[jj] = (j < jend) ? acc : -1e30f;
        }

        float tmax = p[0];
        #pragma unroll
        for (int jj = 1; jj < 8; jj++) tmax = fmaxf(tmax, p[jj]);
        tmax = fmaxf(tmax, __shfl_xor(tmax, 1));
        tmax = fmaxf(tmax, __shfl_xor(tmax, 2));
        tmax = fmaxf(tmax, __shfl_xor(tmax, 4));
        const float mn   = fmaxf(m, tmax);
        const float corr = __expf(m - mn);
        m = mn;

        float ls = 0.0f;
        #pragma unroll
        for (int jj = 0; jj < 8; jj++) { p[jj] = __expf(p[jj] - mn); ls += p[jj]; }
        l = l * corr + ls;

        #pragma unroll
        for (int d = 0; d < 32; d++) o[d] *= corr;
        #pragma unroll
        for (int jj = 0; jj < 8; jj++) {
            const int j = jj * 8 + grp;
            const float* vr = &Vt[j][0];
            const float pe = p[jj];
            #pragma unroll
            for (int d = 0; d < 32; d++) o[d] += pe * vr[d];
        }
    }

    // combine the 8 per-grp partials of each row (same m on all lanes)
    l += __shfl_xor(l, 1); l += __shfl_xor(l, 2); l += __shfl_xor(l, 4);
    #pragma unroll
    for (int d = 0; d < 32; d++) {
        float v = o[d];
        v += __shfl_xor(v, 1); v += __shfl_xor(v, 2); v += __shfl_xor(v, 4);
        o[d] = v;
    }
    const float inv = 1.0f / l;
    float4 ov;
    ov.x = o[grp*4+0] * inv; ov.y = o[grp*4+1] * inv;
    ov.z = o[grp*4+2] * inv; ov.w = o[grp*4+3] * inv;
    *((float4*)(O + ((size_t)(b * LL + ig)) * HIDD + h * HDD) + grp) = ov;
}

// ---------------------------------------------------------------------------
// Kernel 3: mean-pool over forces (commutes with o-proj) -> o-proj -> LN ->
// f-proj -> SiLU -> fp32 out. Block per (t, b), 128 threads (one per channel).
// ---------------------------------------------------------------------------
__global__ __launch_bounds__(128) void final_kernel(
    const float* __restrict__ A,
    const float* __restrict__ o_w,    const float* __restrict__ o_b,
    const float* __restrict__ f_ln_w, const float* __restrict__ f_ln_b,
    const float* __restrict__ f_w,    const float* __restrict__ f_b,
    float* __restrict__ out)
{
    const int t = blockIdx.x;
    const int b = blockIdx.y;
    const int d = threadIdx.x;   // 0..127

    __shared__ float ms[HIDD];
    __shared__ float lnbuf[HIDD];
    __shared__ float w1[2], w2[2];

    float acc = 0.0f;
    #pragma unroll
    for (int f = 0; f < NF; f++)
        acc += A[((size_t)(b * LL + t * NF + f)) * HIDD + d];
    acc *= (1.0f / NF);
    ms[d] = acc;
    __syncthreads();

    float ov = o_b[d];
    for (int k = 0; k < HIDD; k++) ov += ms[k] * o_w[k * HIDD + d];

    float s1 = ov, s2 = ov * ov;
    #pragma unroll
    for (int m = 32; m >= 1; m >>= 1) { s1 += __shfl_xor(s1, m); s2 += __shfl_xor(s2, m); }
    if ((d & 63) == 0) { w1[d >> 6] = s1; w2[d >> 6] = s2; }
    __syncthreads();
    float S1 = w1[0] + w1[1], S2 = w2[0] + w2[1];
    float mu  = S1 * (1.0f / HIDD);
    float var = S2 * (1.0f / HIDD) - mu * mu;
    float r   = rsqrtf(var + EPSF);
    float lnv = (ov - mu) * r * f_ln_w[d] + f_ln_b[d];
    lnbuf[d] = lnv;
    __syncthreads();

    float fv = f_b[d];
    for (int k = 0; k < HIDD; k++) fv += lnbuf[k] * f_w[k * HIDD + d];
    fv = fv / (1.0f + __expf(-fv));   // SiLU

    out[((size_t)(b * TT + t)) * FDD + d] = fv;
}

// ---------------------------------------------------------------------------
extern "C" void kernel_launch(void* const* d_in, const int* in_sizes, int n_in,
                              void* d_out, int out_size, void* d_ws, size_t ws_size,
                              hipStream_t stream)
{
    const float* x      = (const float*)d_in[0];
    const float* g_ln_w = (const float*)d_in[1];
    const float* g_ln_b = (const float*)d_in[2];
    const float* g_w1   = (const float*)d_in[3];
    const float* g_b1   = (const float*)d_in[4];
    const float* g_w2   = (const float*)d_in[5];
    const float* g_b2   = (const float*)d_in[6];
    const float* q_w    = (const float*)d_in[7];
    const float* q_b    = (const float*)d_in[8];
    const float* k_w    = (const float*)d_in[9];
    const float* k_b    = (const float*)d_in[10];
    const float* v_w    = (const float*)d_in[11];
    const float* v_b    = (const float*)d_in[12];
    const float* o_w    = (const float*)d_in[13];
    const float* o_b    = (const float*)d_in[14];
    const float* f_ln_w = (const float*)d_in[15];
    const float* f_ln_b = (const float*)d_in[16];
    const float* f_w    = (const float*)d_in[17];
    const float* f_b    = (const float*)d_in[18];

    const size_t stride = (size_t)BB * LL * HIDD;   // 786432 floats
    float* Qw = (float*)d_ws;
    float* Kw = Qw + stride;
    float* Vw = Kw + stride;
    float* Aw = Vw + stride;                        // total 12.6 MB of d_ws

    gate_qkv_kernel<<<BB * LL, 64, 0, stream>>>(
        x, g_ln_w, g_ln_b, g_w1, g_b1, g_w2, g_b2,
        q_w, q_b, k_w, k_b, v_w, v_b, Qw, Kw, Vw);

    attn_kernel<<<dim3(LL / 32, NHH, BB), 256, 0, stream>>>(Qw, Kw, Vw, Aw);

    final_kernel<<<dim3(TT, BB), 128, 0, stream>>>(
        Aw, o_w, o_b, f_ln_w, f_ln_b, f_w, f_b, (float*)d_out);
}